// Round 6
// baseline (17705.502 us; speedup 1.0000x reference)
//
#include <hip/hip_runtime.h>

// Two-layer tanh RNN, persistent kernel (plain launch), MFMA bf16, epoch sync.
// 64 WGs x 256 thr: layer = wg>>5, rr = wg&31, n_blk = rr&15 (64 feats),
// m_blk = rr>>4 (32 rows). Wave wv = 16-feature slice.
// Critical-path weights VGPR-resident (L0: Wh0, L1: Wi1; 128 VGPRs).
// Pre-wait part streams its weights (Wi0 / Wh1, bf16 in ws, L2-hot).
// MFMA A=weights, B=activations -> D=[feat][row]; lane owns 4 consecutive
// feats x 1 row -> direct 8B ring packs + float4 out stores, no LDS.
// Sync: per-WG epoch u32 per (m_blk,layer) group of 16 (64B line);
// producer: ring stores -> s_waitcnt vmcnt(0) -> barrier -> epoch store.
// consumer: tid0 fresh min-scan polls; 4-deep rings.
//   L0@s: minL0>=s (h1[s-1]); minL1>=s-3 (WAR)
//   L1@s: minL1>=s (h2[s-1]); pre-part; minL0>=s+1 (h1[s]); critical part.

#define SEQ 512
#define BATCH 64
#define HID 1024
#define BH (BATCH * HID)

typedef __attribute__((ext_vector_type(8))) short short8;
typedef __attribute__((ext_vector_type(4))) float f32x4;

__device__ __forceinline__ unsigned short f32_to_bf16_rne(float f) {
    unsigned int u = __float_as_uint(f);
    u += 0x7FFFu + ((u >> 16) & 1u);
    return (unsigned short)(u >> 16);
}

__device__ __forceinline__ short8 cvt8(float4 f0, float4 f1) {
    short8 w;
    w[0] = (short)f32_to_bf16_rne(f0.x);
    w[1] = (short)f32_to_bf16_rne(f0.y);
    w[2] = (short)f32_to_bf16_rne(f0.z);
    w[3] = (short)f32_to_bf16_rne(f0.w);
    w[4] = (short)f32_to_bf16_rne(f1.x);
    w[5] = (short)f32_to_bf16_rne(f1.y);
    w[6] = (short)f32_to_bf16_rne(f1.z);
    w[7] = (short)f32_to_bf16_rne(f1.w);
    return w;
}

// bf16-preferred / f32-fallback 8-element load (uniform branch)
__device__ __forceinline__ short8 ld_s8(const unsigned short* pb, const float* pf, int off) {
    if (pb) return *(const short8*)(pb + off);
    return cvt8(*(const float4*)(pf + off), *(const float4*)(pf + off + 4));
}

struct Q2 { unsigned long long lo, hi; };

__device__ __forceinline__ short8 ld_ring16(const unsigned short* p) {
    Q2 q;
    q.lo = __hip_atomic_load((const unsigned long long*)p,
                             __ATOMIC_RELAXED, __HIP_MEMORY_SCOPE_AGENT);
    q.hi = __hip_atomic_load(((const unsigned long long*)p) + 1,
                             __ATOMIC_RELAXED, __HIP_MEMORY_SCOPE_AGENT);
    return __builtin_bit_cast(short8, q);
}

__device__ __forceinline__ unsigned long long pack4_bf16(float a, float b, float c, float d) {
    return (unsigned long long)f32_to_bf16_rne(a)
         | ((unsigned long long)f32_to_bf16_rne(b) << 16)
         | ((unsigned long long)f32_to_bf16_rne(c) << 32)
         | ((unsigned long long)f32_to_bf16_rne(d) << 48);
}

__device__ __forceinline__ int poll_min16(const unsigned long long* p) {
    unsigned mn = 0xFFFFFFFFu;
    #pragma unroll
    for (int i = 0; i < 8; ++i) {
        unsigned long long v = __hip_atomic_load(p + i, __ATOMIC_RELAXED,
                                                 __HIP_MEMORY_SCOPE_AGENT);
        unsigned a = (unsigned)v, b = (unsigned)(v >> 32);
        mn = mn < a ? mn : a;
        mn = mn < b ? mn : b;
    }
    return (int)mn;
}

__device__ __forceinline__ void wait_min(const unsigned long long* p, int target) {
    if (target <= 0) return;
    while (poll_min16(p) < target) __builtin_amdgcn_s_sleep(1);
}

__global__ void cvt_f32_bf16(const float* __restrict__ src,
                             unsigned short* __restrict__ dst, int n4) {
    int i = blockIdx.x * blockDim.x + threadIdx.x;
    int stride = gridDim.x * blockDim.x;
    for (; i < n4; i += stride) {
        float4 f = ((const float4*)src)[i];
        ushort4 o;
        o.x = f32_to_bf16_rne(f.x);
        o.y = f32_to_bf16_rne(f.y);
        o.z = f32_to_bf16_rne(f.z);
        o.w = f32_to_bf16_rne(f.w);
        ((ushort4*)dst)[i] = o;
    }
}

__global__ void init_ws(uint4* __restrict__ p, int n16) {
    int i = blockIdx.x * blockDim.x + threadIdx.x;
    if (i < n16) p[i] = make_uint4(0u, 0u, 0u, 0u);
}

#define MFMA16(W, A, ACC) \
    ACC = __builtin_amdgcn_mfma_f32_16x16x32_bf16((W), (A), (ACC), 0, 0, 0)

__global__ __launch_bounds__(256, 1) void rnn_mfma(
    const float* __restrict__ x,
    const unsigned short* __restrict__ xb, int use_xb,
    const unsigned short* __restrict__ wb0,   // Wi0 bf16 (streamed, L0 pre)
    const unsigned short* __restrict__ wb1,   // Wh1 bf16 (streamed, L1 pre)
    int use_wb,
    const float* __restrict__ Wi0, const float* __restrict__ bi0,
    const float* __restrict__ Wh0, const float* __restrict__ bh0,
    const float* __restrict__ Wi1, const float* __restrict__ bi1,
    const float* __restrict__ Wh1, const float* __restrict__ bh1,
    float* __restrict__ out,
    unsigned short* __restrict__ rings,
    unsigned int* __restrict__ flags)
{
    unsigned short* h1ring = rings;              // [4][64][1024] bf16
    unsigned short* h2ring = rings + 4 * BH;     // [4][64][1024] bf16

    const int tid   = threadIdx.x;
    const int wg    = blockIdx.x;    // 0..63
    const int layer = wg >> 5;
    const int rr    = wg & 31;
    const int n_blk = rr & 15;       // 64-feature block
    const int m_blk = rr >> 4;       // 32-row batch half
    const int wv    = tid >> 6;      // wave -> 16-feature slice
    const int lane  = tid & 63;

    unsigned int* ep_self = flags + (m_blk * 2 + layer) * 16 + n_blk;
    const unsigned long long* epL0 = (const unsigned long long*)(flags + (m_blk * 2 + 0) * 16);
    const unsigned long long* epL1 = (const unsigned long long*)(flags + (m_blk * 2 + 1) * 16);

    const int fg_w = n_blk * 64 + wv * 16 + (lane & 15);
    const int kcol = (lane >> 4) * 8;

    // ---- resident weights: critical-path matrix (L0: Wh0, L1: Wi1) ----
    short8 wreg[32];
    {
        const float* Wres = layer ? Wi1 : Wh0;
        const float* rw = Wres + (size_t)fg_w * HID + kcol;
        #pragma unroll
        for (int ks = 0; ks < 32; ++ks)
            wreg[ks] = cvt8(*(const float4*)(rw + ks * 32),
                            *(const float4*)(rw + ks * 32 + 4));
    }

    // streamed-weight row pointers (pre-wait matmul)
    const unsigned short* swb = use_wb
        ? (layer ? wb1 : wb0) + (size_t)fg_w * HID + kcol : nullptr;
    const float* swf = (layer ? Wh1 : Wi0) + (size_t)fg_w * HID + kcol;

    // each lane outputs 4 consecutive feats (fb..fb+3) for rows row0/row1
    const int fb = n_blk * 64 + wv * 16 + 4 * (lane >> 4);
    const float* biv = layer ? bi1 : bi0;
    const float* bhv = layer ? bh1 : bh0;
    float bias4[4];
    #pragma unroll
    for (int r = 0; r < 4; ++r) bias4[r] = biv[fb + r] + bhv[fb + r];

    const int row0 = m_blk * 32 + (lane & 15);
    const int row1 = row0 + 16;
    const size_t aoff0 = (size_t)row0 * HID + kcol;
    const size_t aoff1 = (size_t)row1 * HID + kcol;

    for (int s = 0; s < SEQ; ++s) {
        f32x4 acc0 = {0.f, 0.f, 0.f, 0.f};
        f32x4 acc1 = {0.f, 0.f, 0.f, 0.f};

        if (layer == 0) {
            // ---- pre-wait: x_s @ Wi0^T (static input, streamed weights) ----
            const unsigned short* pb0 = use_xb ? xb + (size_t)s * BH + aoff0 : nullptr;
            const unsigned short* pb1 = use_xb ? xb + (size_t)s * BH + aoff1 : nullptr;
            const float* pf0 = x + (size_t)s * BH + aoff0;
            const float* pf1 = x + (size_t)s * BH + aoff1;
            #pragma unroll
            for (int ks = 0; ks < 32; ++ks) {
                short8 wf = ld_s8(swb, swf, ks * 32);
                short8 a0 = ld_s8(pb0, pf0, ks * 32);
                short8 a1 = ld_s8(pb1, pf1, ks * 32);
                MFMA16(wf, a0, acc0);
                MFMA16(wf, a1, acc1);
            }
            // ---- wait: h1[s-1] complete; L1 consumed h1[s-4] (ring WAR) ----
            if (tid == 0) {
                wait_min(epL0, s);
                wait_min(epL1, s - 3);
            }
            __syncthreads();
            asm volatile("" ::: "memory");
            // ---- critical: h1[s-1] @ Wh0^T (resident weights) ----
            const unsigned short* pr = h1ring + (size_t)((s - 1) & 3) * BH;
            #pragma unroll
            for (int ks = 0; ks < 32; ++ks) {
                short8 a0 = ld_ring16(pr + aoff0 + ks * 32);
                short8 a1 = ld_ring16(pr + aoff1 + ks * 32);
                MFMA16(wreg[ks], a0, acc0);
                MFMA16(wreg[ks], a1, acc1);
            }
        } else {
            // ---- wait1 (usually satisfied): h2[s-1] done ----
            if (tid == 0) wait_min(epL1, s);
            __syncthreads();
            asm volatile("" ::: "memory");
            // ---- pre-part: h2[s-1] @ Wh1^T (streamed weights) ----
            const unsigned short* pr2 = h2ring + (size_t)((s - 1) & 3) * BH;
            #pragma unroll
            for (int ks = 0; ks < 32; ++ks) {
                short8 wf = ld_s8(swb, swf, ks * 32);
                short8 a0 = ld_ring16(pr2 + aoff0 + ks * 32);
                short8 a1 = ld_ring16(pr2 + aoff1 + ks * 32);
                MFMA16(wf, a0, acc0);
                MFMA16(wf, a1, acc1);
            }
            // ---- wait2 (critical): h1[s] done ----
            if (tid == 0) wait_min(epL0, s + 1);
            __syncthreads();
            asm volatile("" ::: "memory");
            // ---- critical: h1[s] @ Wi1^T (resident weights) ----
            const unsigned short* pr1 = h1ring + (size_t)(s & 3) * BH;
            #pragma unroll
            for (int ks = 0; ks < 32; ++ks) {
                short8 a0 = ld_ring16(pr1 + aoff0 + ks * 32);
                short8 a1 = ld_ring16(pr1 + aoff1 + ks * 32);
                MFMA16(wreg[ks], a0, acc0);
                MFMA16(wreg[ks], a1, acc1);
            }
        }

        // ---- bias + tanh + ring store (critical) ----
        float v0[4], v1[4];
        #pragma unroll
        for (int r = 0; r < 4; ++r) {
            v0[r] = tanhf(acc0[r] + bias4[r]);
            v1[r] = tanhf(acc1[r] + bias4[r]);
        }
        unsigned short* ring_self = (layer ? h2ring : h1ring) + (size_t)(s & 3) * BH;
        __hip_atomic_store((unsigned long long*)(ring_self + (size_t)row0 * HID + fb),
                           pack4_bf16(v0[0], v0[1], v0[2], v0[3]),
                           __ATOMIC_RELAXED, __HIP_MEMORY_SCOPE_AGENT);
        __hip_atomic_store((unsigned long long*)(ring_self + (size_t)row1 * HID + fb),
                           pack4_bf16(v1[0], v1[1], v1[2], v1[3]),
                           __ATOMIC_RELAXED, __HIP_MEMORY_SCOPE_AGENT);

        asm volatile("s_waitcnt vmcnt(0)" ::: "memory");   // ring stores visible
        __syncthreads();                                   // all waves acked
        if (tid == 0)
            __hip_atomic_store(ep_self, (unsigned)(s + 1),
                               __ATOMIC_RELAXED, __HIP_MEMORY_SCOPE_AGENT);

        // ---- f32 outputs (off critical path, after signal) ----
        if (layer == 1) {
            *(float4*)(out + (size_t)s * BH + (size_t)row0 * HID + fb) =
                make_float4(v0[0], v0[1], v0[2], v0[3]);
            *(float4*)(out + (size_t)s * BH + (size_t)row1 * HID + fb) =
                make_float4(v1[0], v1[1], v1[2], v1[3]);
            if (s == SEQ - 1) {
                *(float4*)(out + (size_t)SEQ * BH + BH + (size_t)row0 * HID + fb) =
                    make_float4(v0[0], v0[1], v0[2], v0[3]);
                *(float4*)(out + (size_t)SEQ * BH + BH + (size_t)row1 * HID + fb) =
                    make_float4(v1[0], v1[1], v1[2], v1[3]);
            }
        } else if (s == SEQ - 1) {
            *(float4*)(out + (size_t)SEQ * BH + (size_t)row0 * HID + fb) =
                make_float4(v0[0], v0[1], v0[2], v0[3]);
            *(float4*)(out + (size_t)SEQ * BH + (size_t)row1 * HID + fb) =
                make_float4(v1[0], v1[1], v1[2], v1[3]);
        }
    }
}

extern "C" void kernel_launch(void* const* d_in, const int* in_sizes, int n_in,
                              void* d_out, int out_size, void* d_ws, size_t ws_size,
                              hipStream_t stream) {
    const float* xp   = (const float*)d_in[0];
    const float* Wi0p = (const float*)d_in[1];
    const float* bi0p = (const float*)d_in[2];
    const float* Wh0p = (const float*)d_in[3];
    const float* bh0p = (const float*)d_in[4];
    const float* Wi1p = (const float*)d_in[5];
    const float* bi1p = (const float*)d_in[6];
    const float* Wh1p = (const float*)d_in[7];
    const float* bh1p = (const float*)d_in[8];
    float* outp = (float*)d_out;

    // ws layout: rings 1 MiB | flags 4 KiB | xb 64 MiB | wb0 2 MiB | wb1 2 MiB
    unsigned short* rings = (unsigned short*)d_ws;
    const size_t ring_bytes = (size_t)8 * BH * sizeof(unsigned short);  // 1 MiB
    unsigned int* flags = (unsigned int*)((char*)d_ws + ring_bytes);
    const size_t flag_pad = 4096;
    unsigned short* xb = (unsigned short*)((char*)d_ws + ring_bytes + flag_pad);
    const size_t xb_bytes = (size_t)SEQ * BH * 2;                        // 64 MiB
    unsigned short* wb0 = (unsigned short*)((char*)xb + xb_bytes);
    const size_t w_bytes = (size_t)HID * HID * 2;                        // 2 MiB
    unsigned short* wb1 = (unsigned short*)((char*)wb0 + w_bytes);

    const int use_xb = (ws_size >= ring_bytes + flag_pad + xb_bytes) ? 1 : 0;
    const int use_wb = (ws_size >= ring_bytes + flag_pad + xb_bytes + 2 * w_bytes) ? 1 : 0;

    {
        const int n16 = (int)((ring_bytes + flag_pad) / 16);
        init_ws<<<(n16 + 255) / 256, 256, 0, stream>>>((uint4*)d_ws, n16);
    }
    if (use_xb)
        cvt_f32_bf16<<<2048, 256, 0, stream>>>(xp, xb, SEQ * BH / 4);
    if (use_wb) {
        cvt_f32_bf16<<<512, 256, 0, stream>>>(Wi0p, wb0, HID * HID / 4);
        cvt_f32_bf16<<<512, 256, 0, stream>>>(Wh1p, wb1, HID * HID / 4);
    }

    rnn_mfma<<<dim3(64), dim3(256), 0, stream>>>(
        xp, xb, use_xb, wb0, wb1, use_wb,
        Wi0p, bi0p, Wh0p, bh0p, Wi1p, bi1p, Wh1p, bh1p,
        outp, rings, flags);
}

// Round 7
// 10720.041 us; speedup vs baseline: 1.6516x; 1.6516x over previous
//
#include <hip/hip_runtime.h>

// Two-layer tanh RNN, persistent kernel (plain launch), MFMA bf16, epoch sync.
// Round-7 delta vs round 6: ring reads + epoch polls use inline-asm
// global_load_dwordx4 sc0 sc1 (MALL-coherent, PIPELINEABLE) issued in batches
// with one vmcnt(0) per chunk, instead of serialized __hip_atomic_load pairs
// (r4/r6 data: each atomic pair exposed ~650cy MALL latency; 128 pairs = 34.7us/step).
//
// 64 WGs x 256 thr: layer = wg>>5, rr = wg&31, n_blk = rr&15 (64 feats),
// m_blk = rr>>4 (32 rows). Wave wv = 16-feature slice, full K=1024 per matmul.
// Critical-path weights VGPR-resident (L0: Wh0, L1: Wi1; 128 VGPRs).
// Pre-wait matmul streams weights (Wi0 / Wh1 bf16 in ws, L2-hot).
// MFMA A=weights, B=activations -> D=[feat][row]; lane owns 4 consecutive
// feats -> 8B ring packs + float4 out stores, no LDS.
// Sync: per-WG epoch u32 per (m_blk,layer) group of 16 (64B line);
// producer: ring stores -> s_waitcnt vmcnt(0) -> barrier -> epoch store.
//   L0@s: minL0>=s (h1[s-1]); minL1>=s-3 (ring WAR, depth 4)
//   L1@s: minL1>=s (h2[s-1]); pre-part; minL0>=s+1 (h1[s]); critical part.

#define SEQ 512
#define BATCH 64
#define HID 1024
#define BH (BATCH * HID)

typedef __attribute__((ext_vector_type(8))) short short8;
typedef __attribute__((ext_vector_type(4))) float f32x4;
typedef __attribute__((ext_vector_type(4))) unsigned int u32x4;

__device__ __forceinline__ unsigned short f32_to_bf16_rne(float f) {
    unsigned int u = __float_as_uint(f);
    u += 0x7FFFu + ((u >> 16) & 1u);
    return (unsigned short)(u >> 16);
}

__device__ __forceinline__ short8 cvt8(float4 f0, float4 f1) {
    short8 w;
    w[0] = (short)f32_to_bf16_rne(f0.x);
    w[1] = (short)f32_to_bf16_rne(f0.y);
    w[2] = (short)f32_to_bf16_rne(f0.z);
    w[3] = (short)f32_to_bf16_rne(f0.w);
    w[4] = (short)f32_to_bf16_rne(f1.x);
    w[5] = (short)f32_to_bf16_rne(f1.y);
    w[6] = (short)f32_to_bf16_rne(f1.z);
    w[7] = (short)f32_to_bf16_rne(f1.w);
    return w;
}

// bf16-preferred / f32-fallback 8-element load (uniform branch)
__device__ __forceinline__ short8 ld_s8(const unsigned short* pb, const float* pf, int off) {
    if (pb) return *(const short8*)(pb + off);
    return cvt8(*(const float4*)(pf + off), *(const float4*)(pf + off + 4));
}

// 16B device-coherent load (bypass L1/L2, served at MALL) — pipelineable,
// no implicit waitcnt: caller must vm_wait0() before using the result.
__device__ __forceinline__ void ld_cc16(short8& d, const unsigned short* p) {
    asm volatile("global_load_dwordx4 %0, %1, off sc0 sc1"
                 : "=v"(d) : "v"(p) : "memory");
}

__device__ __forceinline__ void vm_wait0() {
    asm volatile("s_waitcnt vmcnt(0)" ::: "memory");
    __builtin_amdgcn_sched_barrier(0);   // rule 18: keep MFMAs below the wait
}

__device__ __forceinline__ unsigned long long pack4_bf16(float a, float b, float c, float d) {
    return (unsigned long long)f32_to_bf16_rne(a)
         | ((unsigned long long)f32_to_bf16_rne(b) << 16)
         | ((unsigned long long)f32_to_bf16_rne(c) << 32)
         | ((unsigned long long)f32_to_bf16_rne(d) << 48);
}

// min over 16 epoch slots: 4 pipelined coherent loads + one wait
__device__ __forceinline__ int poll_min16(const unsigned int* f) {
    u32x4 a, b, c, d;
    asm volatile("global_load_dwordx4 %0, %4, off sc0 sc1\n\t"
                 "global_load_dwordx4 %1, %5, off sc0 sc1\n\t"
                 "global_load_dwordx4 %2, %6, off sc0 sc1\n\t"
                 "global_load_dwordx4 %3, %7, off sc0 sc1\n\t"
                 "s_waitcnt vmcnt(0)"
                 : "=v"(a), "=v"(b), "=v"(c), "=v"(d)
                 : "v"(f), "v"(f + 4), "v"(f + 8), "v"(f + 12)
                 : "memory");
    unsigned mn = a[0];
    #pragma unroll
    for (int i = 1; i < 4; ++i) mn = mn < a[i] ? mn : a[i];
    #pragma unroll
    for (int i = 0; i < 4; ++i) mn = mn < b[i] ? mn : b[i];
    #pragma unroll
    for (int i = 0; i < 4; ++i) mn = mn < c[i] ? mn : c[i];
    #pragma unroll
    for (int i = 0; i < 4; ++i) mn = mn < d[i] ? mn : d[i];
    return (int)mn;
}

__device__ __forceinline__ void wait_min(const unsigned int* f, int target) {
    if (target <= 0) return;
    while (poll_min16(f) < target) __builtin_amdgcn_s_sleep(1);
}

__global__ void cvt_f32_bf16(const float* __restrict__ src,
                             unsigned short* __restrict__ dst, int n4) {
    int i = blockIdx.x * blockDim.x + threadIdx.x;
    int stride = gridDim.x * blockDim.x;
    for (; i < n4; i += stride) {
        float4 f = ((const float4*)src)[i];
        ushort4 o;
        o.x = f32_to_bf16_rne(f.x);
        o.y = f32_to_bf16_rne(f.y);
        o.z = f32_to_bf16_rne(f.z);
        o.w = f32_to_bf16_rne(f.w);
        ((ushort4*)dst)[i] = o;
    }
}

__global__ void init_ws(uint4* __restrict__ p, int n16) {
    int i = blockIdx.x * blockDim.x + threadIdx.x;
    if (i < n16) p[i] = make_uint4(0u, 0u, 0u, 0u);
}

#define MFMA16(W, A, ACC) \
    ACC = __builtin_amdgcn_mfma_f32_16x16x32_bf16((W), (A), (ACC), 0, 0, 0)

__global__ __launch_bounds__(256, 1) void rnn_mfma(
    const float* __restrict__ x,
    const unsigned short* __restrict__ xb, int use_xb,
    const unsigned short* __restrict__ wb0,   // Wi0 bf16 (streamed, L0 pre)
    const unsigned short* __restrict__ wb1,   // Wh1 bf16 (streamed, L1 pre)
    int use_wb,
    const float* __restrict__ Wi0, const float* __restrict__ bi0,
    const float* __restrict__ Wh0, const float* __restrict__ bh0,
    const float* __restrict__ Wi1, const float* __restrict__ bi1,
    const float* __restrict__ Wh1, const float* __restrict__ bh1,
    float* __restrict__ out,
    unsigned short* __restrict__ rings,
    unsigned int* __restrict__ flags)
{
    unsigned short* h1ring = rings;              // [4][64][1024] bf16
    unsigned short* h2ring = rings + 4 * BH;     // [4][64][1024] bf16

    const int tid   = threadIdx.x;
    const int wg    = blockIdx.x;    // 0..63
    const int layer = wg >> 5;
    const int rr    = wg & 31;
    const int n_blk = rr & 15;       // 64-feature block
    const int m_blk = rr >> 4;       // 32-row batch half
    const int wv    = tid >> 6;      // wave -> 16-feature slice
    const int lane  = tid & 63;

    unsigned int* ep_self = flags + (m_blk * 2 + layer) * 16 + n_blk;
    const unsigned int* epL0 = flags + (m_blk * 2 + 0) * 16;
    const unsigned int* epL1 = flags + (m_blk * 2 + 1) * 16;

    const int fg_w = n_blk * 64 + wv * 16 + (lane & 15);
    const int kcol = (lane >> 4) * 8;

    // ---- resident weights: critical-path matrix (L0: Wh0, L1: Wi1) ----
    short8 wreg[32];
    {
        const float* Wres = layer ? Wi1 : Wh0;
        const float* rw = Wres + (size_t)fg_w * HID + kcol;
        #pragma unroll
        for (int ks = 0; ks < 32; ++ks)
            wreg[ks] = cvt8(*(const float4*)(rw + ks * 32),
                            *(const float4*)(rw + ks * 32 + 4));
    }

    // streamed-weight row pointers (pre-wait matmul)
    const unsigned short* swb = use_wb
        ? (layer ? wb1 : wb0) + (size_t)fg_w * HID + kcol : nullptr;
    const float* swf = (layer ? Wh1 : Wi0) + (size_t)fg_w * HID + kcol;

    // each lane outputs 4 consecutive feats (fb..fb+3) for rows row0/row1
    const int fb = n_blk * 64 + wv * 16 + 4 * (lane >> 4);
    const float* biv = layer ? bi1 : bi0;
    const float* bhv = layer ? bh1 : bh0;
    float bias4[4];
    #pragma unroll
    for (int r = 0; r < 4; ++r) bias4[r] = biv[fb + r] + bhv[fb + r];

    const int row0 = m_blk * 32 + (lane & 15);
    const int row1 = row0 + 16;
    const size_t aoff0 = (size_t)row0 * HID + kcol;
    const size_t aoff1 = (size_t)row1 * HID + kcol;

    for (int s = 0; s < SEQ; ++s) {
        f32x4 acc0 = {0.f, 0.f, 0.f, 0.f};
        f32x4 acc1 = {0.f, 0.f, 0.f, 0.f};

        if (layer == 0) {
            // ---- pre-wait: x_s @ Wi0^T (static input, streamed weights) ----
            const unsigned short* pb0 = use_xb ? xb + (size_t)s * BH + aoff0 : nullptr;
            const unsigned short* pb1 = use_xb ? xb + (size_t)s * BH + aoff1 : nullptr;
            const float* pf0 = x + (size_t)s * BH + aoff0;
            const float* pf1 = x + (size_t)s * BH + aoff1;
            #pragma unroll
            for (int ks = 0; ks < 32; ++ks) {
                short8 wf = ld_s8(swb, swf, ks * 32);
                short8 a0 = ld_s8(pb0, pf0, ks * 32);
                short8 a1 = ld_s8(pb1, pf1, ks * 32);
                MFMA16(wf, a0, acc0);
                MFMA16(wf, a1, acc1);
            }
            // ---- wait: h1[s-1] complete; L1 consumed h1[s-4] (ring WAR) ----
            if (tid == 0) {
                wait_min(epL0, s);
                wait_min(epL1, s - 3);
            }
            __syncthreads();
            asm volatile("" ::: "memory");
            // ---- critical: h1[s-1] @ Wh0^T (resident weights, batched loads) ----
            const unsigned short* pr = h1ring + (size_t)((s - 1) & 3) * BH;
            #pragma unroll
            for (int c = 0; c < 2; ++c) {
                short8 a0[16], a1[16];
                #pragma unroll
                for (int k = 0; k < 16; ++k) {
                    ld_cc16(a0[k], pr + aoff0 + (c * 16 + k) * 32);
                    ld_cc16(a1[k], pr + aoff1 + (c * 16 + k) * 32);
                }
                vm_wait0();
                #pragma unroll
                for (int k = 0; k < 16; ++k) {
                    MFMA16(wreg[c * 16 + k], a0[k], acc0);
                    MFMA16(wreg[c * 16 + k], a1[k], acc1);
                }
            }
        } else {
            // ---- wait1 (usually satisfied): h2[s-1] done ----
            if (tid == 0) wait_min(epL1, s);
            __syncthreads();
            asm volatile("" ::: "memory");
            // ---- pre-part: h2[s-1] @ Wh1^T (streamed weights, batched loads) ----
            const unsigned short* pr2 = h2ring + (size_t)((s - 1) & 3) * BH;
            #pragma unroll
            for (int c = 0; c < 4; ++c) {
                short8 wf[8], a0[8], a1[8];
                #pragma unroll
                for (int k = 0; k < 8; ++k)
                    wf[k] = ld_s8(swb, swf, (c * 8 + k) * 32);   // plain, pipelined
                #pragma unroll
                for (int k = 0; k < 8; ++k) {
                    ld_cc16(a0[k], pr2 + aoff0 + (c * 8 + k) * 32);
                    ld_cc16(a1[k], pr2 + aoff1 + (c * 8 + k) * 32);
                }
                vm_wait0();
                #pragma unroll
                for (int k = 0; k < 8; ++k) {
                    MFMA16(wf[k], a0[k], acc0);
                    MFMA16(wf[k], a1[k], acc1);
                }
            }
            // ---- wait2 (critical): h1[s] done ----
            if (tid == 0) wait_min(epL0, s + 1);
            __syncthreads();
            asm volatile("" ::: "memory");
            // ---- critical: h1[s] @ Wi1^T (resident weights, batched loads) ----
            const unsigned short* pr1 = h1ring + (size_t)(s & 3) * BH;
            #pragma unroll
            for (int c = 0; c < 2; ++c) {
                short8 a0[16], a1[16];
                #pragma unroll
                for (int k = 0; k < 16; ++k) {
                    ld_cc16(a0[k], pr1 + aoff0 + (c * 16 + k) * 32);
                    ld_cc16(a1[k], pr1 + aoff1 + (c * 16 + k) * 32);
                }
                vm_wait0();
                #pragma unroll
                for (int k = 0; k < 16; ++k) {
                    MFMA16(wreg[c * 16 + k], a0[k], acc0);
                    MFMA16(wreg[c * 16 + k], a1[k], acc1);
                }
            }
        }

        // ---- bias + tanh + ring store (critical) ----
        float v0[4], v1[4];
        #pragma unroll
        for (int r = 0; r < 4; ++r) {
            v0[r] = tanhf(acc0[r] + bias4[r]);
            v1[r] = tanhf(acc1[r] + bias4[r]);
        }
        unsigned short* ring_self = (layer ? h2ring : h1ring) + (size_t)(s & 3) * BH;
        __hip_atomic_store((unsigned long long*)(ring_self + (size_t)row0 * HID + fb),
                           pack4_bf16(v0[0], v0[1], v0[2], v0[3]),
                           __ATOMIC_RELAXED, __HIP_MEMORY_SCOPE_AGENT);
        __hip_atomic_store((unsigned long long*)(ring_self + (size_t)row1 * HID + fb),
                           pack4_bf16(v1[0], v1[1], v1[2], v1[3]),
                           __ATOMIC_RELAXED, __HIP_MEMORY_SCOPE_AGENT);

        asm volatile("s_waitcnt vmcnt(0)" ::: "memory");   // ring data at MALL
        __syncthreads();                                   // all waves acked
        if (tid == 0)
            __hip_atomic_store(ep_self, (unsigned)(s + 1),
                               __ATOMIC_RELAXED, __HIP_MEMORY_SCOPE_AGENT);

        // ---- f32 outputs (off critical path, after signal) ----
        if (layer == 1) {
            *(float4*)(out + (size_t)s * BH + (size_t)row0 * HID + fb) =
                make_float4(v0[0], v0[1], v0[2], v0[3]);
            *(float4*)(out + (size_t)s * BH + (size_t)row1 * HID + fb) =
                make_float4(v1[0], v1[1], v1[2], v1[3]);
            if (s == SEQ - 1) {
                *(float4*)(out + (size_t)SEQ * BH + BH + (size_t)row0 * HID + fb) =
                    make_float4(v0[0], v0[1], v0[2], v0[3]);
                *(float4*)(out + (size_t)SEQ * BH + BH + (size_t)row1 * HID + fb) =
                    make_float4(v1[0], v1[1], v1[2], v1[3]);
            }
        } else if (s == SEQ - 1) {
            *(float4*)(out + (size_t)SEQ * BH + (size_t)row0 * HID + fb) =
                make_float4(v0[0], v0[1], v0[2], v0[3]);
            *(float4*)(out + (size_t)SEQ * BH + (size_t)row1 * HID + fb) =
                make_float4(v1[0], v1[1], v1[2], v1[3]);
        }
    }
}

extern "C" void kernel_launch(void* const* d_in, const int* in_sizes, int n_in,
                              void* d_out, int out_size, void* d_ws, size_t ws_size,
                              hipStream_t stream) {
    const float* xp   = (const float*)d_in[0];
    const float* Wi0p = (const float*)d_in[1];
    const float* bi0p = (const float*)d_in[2];
    const float* Wh0p = (const float*)d_in[3];
    const float* bh0p = (const float*)d_in[4];
    const float* Wi1p = (const float*)d_in[5];
    const float* bi1p = (const float*)d_in[6];
    const float* Wh1p = (const float*)d_in[7];
    const float* bh1p = (const float*)d_in[8];
    float* outp = (float*)d_out;

    // ws layout: rings 1 MiB | flags 4 KiB | xb 64 MiB | wb0 2 MiB | wb1 2 MiB
    unsigned short* rings = (unsigned short*)d_ws;
    const size_t ring_bytes = (size_t)8 * BH * sizeof(unsigned short);  // 1 MiB
    unsigned int* flags = (unsigned int*)((char*)d_ws + ring_bytes);
    const size_t flag_pad = 4096;
    unsigned short* xb = (unsigned short*)((char*)d_ws + ring_bytes + flag_pad);
    const size_t xb_bytes = (size_t)SEQ * BH * 2;                        // 64 MiB
    unsigned short* wb0 = (unsigned short*)((char*)xb + xb_bytes);
    const size_t w_bytes = (size_t)HID * HID * 2;                        // 2 MiB
    unsigned short* wb1 = (unsigned short*)((char*)wb0 + w_bytes);

    const int use_xb = (ws_size >= ring_bytes + flag_pad + xb_bytes) ? 1 : 0;
    const int use_wb = (ws_size >= ring_bytes + flag_pad + xb_bytes + 2 * w_bytes) ? 1 : 0;

    {
        const int n16 = (int)((ring_bytes + flag_pad) / 16);
        init_ws<<<(n16 + 255) / 256, 256, 0, stream>>>((uint4*)d_ws, n16);
    }
    if (use_xb)
        cvt_f32_bf16<<<2048, 256, 0, stream>>>(xp, xb, SEQ * BH / 4);
    if (use_wb) {
        cvt_f32_bf16<<<512, 256, 0, stream>>>(Wi0p, wb0, HID * HID / 4);
        cvt_f32_bf16<<<512, 256, 0, stream>>>(Wh1p, wb1, HID * HID / 4);
    }

    rnn_mfma<<<dim3(64), dim3(256), 0, stream>>>(
        xp, xb, use_xb, wb0, wb1, use_wb,
        Wi0p, bi0p, Wh0p, bh0p, Wi1p, bi1p, Wh1p, bh1p,
        outp, rings, flags);
}

// Round 9
// 4519.833 us; speedup vs baseline: 3.9173x; 2.3718x over previous
//
#include <hip/hip_runtime.h>

// Two-layer tanh RNN, persistent kernel (plain launch), MFMA bf16, epoch sync.
// Round-9 = round-8 + RULE-18 FIX in poll_min64: sched_barrier(0) after the
// vmcnt(0) so the min-reduction cannot be hoisted above the wait (r8 raced:
// stale VGPR reads -> spurious wait pass -> absmax 0.85).
//
// 256 WGs x 256 thr (1 WG/CU): wg = layer*128 + m_blk*64 + n_blk.
//   n_blk: 16 output feats; m_blk: 32 batch rows; wave wv: src=wv>>1, kh=wv&1.
//   Wave = one source matrix x K=512 slice: weights VGPR-resident (16 short8).
// Sources: L0: src0 = x@Wi0 (plain loads, no wait), src1 = h1[s-1]@Wh0.
//          L1: src0 = h1[s]@Wi1 (critical), src1 = h2[s-1]@Wh1 (early).
// Cross-wave K-reduce via LDS (4x16x33 f32), 2 barriers/step.
// Ring reads: inline-asm global_load_dwordx4 sc0 sc1 batched (2 chunks x 16),
// one vmcnt(0)+sched_barrier per chunk.
// Sync: per-(layer,m_blk) epoch group of 64 u32 slots; producer: ring stores
// -> vmcnt(0) -> barrier -> slot store. Consumer lane0 min-scans 16 dwordx4.
//   L0@s: grpL0>=s (h1[s-1]); grpL1>=s-3 (ring WAR, depth 4)
//   L1@s: grpL1>=s (h2[s-1]); grpL0>=s+1 (h1[s])

#define SEQ 512
#define BATCH 64
#define HID 1024
#define BH (BATCH * HID)

typedef __attribute__((ext_vector_type(8))) short short8;
typedef __attribute__((ext_vector_type(4))) float f32x4;
typedef __attribute__((ext_vector_type(4))) unsigned int u32x4;

__device__ __forceinline__ unsigned short f32_to_bf16_rne(float f) {
    unsigned int u = __float_as_uint(f);
    u += 0x7FFFu + ((u >> 16) & 1u);
    return (unsigned short)(u >> 16);
}

__device__ __forceinline__ short8 cvt8(float4 f0, float4 f1) {
    short8 w;
    w[0] = (short)f32_to_bf16_rne(f0.x);
    w[1] = (short)f32_to_bf16_rne(f0.y);
    w[2] = (short)f32_to_bf16_rne(f0.z);
    w[3] = (short)f32_to_bf16_rne(f0.w);
    w[4] = (short)f32_to_bf16_rne(f1.x);
    w[5] = (short)f32_to_bf16_rne(f1.y);
    w[6] = (short)f32_to_bf16_rne(f1.z);
    w[7] = (short)f32_to_bf16_rne(f1.w);
    return w;
}

// 16B device-coherent load (served at MALL), pipelineable; caller waits.
__device__ __forceinline__ void ld_cc16(short8& d, const unsigned short* p) {
    asm volatile("global_load_dwordx4 %0, %1, off sc0 sc1"
                 : "=v"(d) : "v"(p) : "memory");
}

__device__ __forceinline__ void vm_wait0() {
    asm volatile("s_waitcnt vmcnt(0)" ::: "memory");
    __builtin_amdgcn_sched_barrier(0);   // rule 18: keep consumers below the wait
}

__device__ __forceinline__ unsigned long long pack4_bf16(float a, float b, float c, float d) {
    return (unsigned long long)f32_to_bf16_rne(a)
         | ((unsigned long long)f32_to_bf16_rne(b) << 16)
         | ((unsigned long long)f32_to_bf16_rne(c) << 32)
         | ((unsigned long long)f32_to_bf16_rne(d) << 48);
}

// min over 64 epoch slots (256B): 16 pipelined coherent loads + one wait.
// RULE-18: sched_barrier(0) after the waitcnt — the register-only min chain
// would otherwise be hoisted above it (this was round-8's race).
__device__ __forceinline__ int poll_min64(const unsigned int* f) {
    u32x4 r[16];
    #pragma unroll
    for (int i = 0; i < 16; ++i)
        asm volatile("global_load_dwordx4 %0, %1, off sc0 sc1"
                     : "=v"(r[i]) : "v"(f + i * 4) : "memory");
    asm volatile("s_waitcnt vmcnt(0)" ::: "memory");
    __builtin_amdgcn_sched_barrier(0);
    unsigned mn = r[0][0];
    #pragma unroll
    for (int i = 0; i < 16; ++i)
        #pragma unroll
        for (int j = 0; j < 4; ++j)
            mn = mn < r[i][j] ? mn : r[i][j];
    return (int)mn;
}

__device__ __forceinline__ void wait_min64(const unsigned int* f, int target) {
    if (target <= 0) return;
    while (poll_min64(f) < target) __builtin_amdgcn_s_sleep(1);
}

__global__ void cvt_f32_bf16(const float* __restrict__ src,
                             unsigned short* __restrict__ dst, int n4) {
    int i = blockIdx.x * blockDim.x + threadIdx.x;
    int stride = gridDim.x * blockDim.x;
    for (; i < n4; i += stride) {
        float4 f = ((const float4*)src)[i];
        ushort4 o;
        o.x = f32_to_bf16_rne(f.x);
        o.y = f32_to_bf16_rne(f.y);
        o.z = f32_to_bf16_rne(f.z);
        o.w = f32_to_bf16_rne(f.w);
        ((ushort4*)dst)[i] = o;
    }
}

__global__ void init_ws(uint4* __restrict__ p, int n16) {
    int i = blockIdx.x * blockDim.x + threadIdx.x;
    if (i < n16) p[i] = make_uint4(0u, 0u, 0u, 0u);
}

#define MFMA16(W, A, ACC) \
    ACC = __builtin_amdgcn_mfma_f32_16x16x32_bf16((W), (A), (ACC), 0, 0, 0)

__global__ __launch_bounds__(256, 1) void rnn_mfma(
    const float* __restrict__ x,
    const unsigned short* __restrict__ xb, int use_xb,
    const float* __restrict__ Wi0, const float* __restrict__ bi0,
    const float* __restrict__ Wh0, const float* __restrict__ bh0,
    const float* __restrict__ Wi1, const float* __restrict__ bi1,
    const float* __restrict__ Wh1, const float* __restrict__ bh1,
    float* __restrict__ out,
    unsigned short* __restrict__ rings,
    unsigned int* __restrict__ flags)
{
    unsigned short* h1ring = rings;              // [4][64][1024] bf16
    unsigned short* h2ring = rings + 4 * BH;     // [4][64][1024] bf16

    const int tid   = threadIdx.x;
    const int wg    = blockIdx.x;        // 0..255
    const int layer = wg >> 7;           // 0/1
    const int m_blk = (wg >> 6) & 1;     // 0/1 (32 rows)
    const int n_blk = wg & 63;           // 0..63 (16 feats)
    const int wv    = tid >> 6;
    const int lane  = tid & 63;
    const int src   = wv >> 1;           // 0: first source, 1: second
    const int kh    = wv & 1;            // K half
    const int koff  = kh * 512;

    unsigned int* grpL0 = flags + (0 * 2 + m_blk) * 64;
    unsigned int* grpL1 = flags + (1 * 2 + m_blk) * 64;
    unsigned int* ep_self = (layer ? grpL1 : grpL0) + n_blk;

    // ---- resident weights: 16 short8 = 64 VGPRs ----
    const float* Wsel = layer ? (src ? Wh1 : Wi1) : (src ? Wh0 : Wi0);
    const int f_w  = n_blk * 16 + (lane & 15);
    const int kcb  = koff + (lane >> 4) * 8;
    short8 wreg[16];
    {
        const float* rw = Wsel + (size_t)f_w * HID + kcb;
        #pragma unroll
        for (int ks = 0; ks < 16; ++ks)
            wreg[ks] = cvt8(*(const float4*)(rw + ks * 32),
                            *(const float4*)(rw + ks * 32 + 4));
    }

    // activation (B-operand) addresses: rows = batch rows
    const int arow0 = m_blk * 32 + (lane & 15);
    const int arow1 = arow0 + 16;
    const size_t aoff0 = (size_t)arow0 * HID + kcb;
    const size_t aoff1 = (size_t)arow1 * HID + kcb;

    // reduce-phase constants (tid<128: one (4-feat group, row) pack)
    const int r_row = tid & 31;          // 0..31
    const int r_fg  = (tid >> 5) & 3;    // 0..3
    const int nb    = n_blk * 16 + r_fg * 4;
    const int rg    = m_blk * 32 + r_row;
    const float* biv = layer ? bi1 : bi0;
    const float* bhv = layer ? bh1 : bh0;
    float bias4[4];
    #pragma unroll
    for (int j = 0; j < 4; ++j) bias4[j] = biv[nb + j] + bhv[nb + j];

    __shared__ float red[4][16][33];

    for (int s = 0; s < SEQ; ++s) {
        f32x4 acc0 = {0.f, 0.f, 0.f, 0.f};
        f32x4 acc1 = {0.f, 0.f, 0.f, 0.f};

        if (layer == 0 && src == 0) {
            // ---- x_s @ Wi0^T : static input, plain loads, no wait ----
            if (use_xb) {
                const unsigned short* px = xb + (size_t)s * BH;
                #pragma unroll
                for (int ks = 0; ks < 16; ++ks) {
                    short8 a0 = *(const short8*)(px + aoff0 + ks * 32);
                    short8 a1 = *(const short8*)(px + aoff1 + ks * 32);
                    MFMA16(wreg[ks], a0, acc0);
                    MFMA16(wreg[ks], a1, acc1);
                }
            } else {
                const float* px = x + (size_t)s * BH;
                #pragma unroll
                for (int ks = 0; ks < 16; ++ks) {
                    short8 a0 = cvt8(*(const float4*)(px + aoff0 + ks * 32),
                                     *(const float4*)(px + aoff0 + ks * 32 + 4));
                    short8 a1 = cvt8(*(const float4*)(px + aoff1 + ks * 32),
                                     *(const float4*)(px + aoff1 + ks * 32 + 4));
                    MFMA16(wreg[ks], a0, acc0);
                    MFMA16(wreg[ks], a1, acc1);
                }
            }
        } else {
            // ---- ring-sourced matmul: poll, then batched coherent loads ----
            const unsigned short* pr;
            if (layer == 0) {            // src1: h1[s-1] @ Wh0^T
                if (lane == 0) {
                    wait_min64(grpL0, s);
                    wait_min64(grpL1, s - 3);    // ring WAR, depth 4
                }
                pr = h1ring + (size_t)((s - 1) & 3) * BH;
            } else if (src == 1) {       // h2[s-1] @ Wh1^T (early)
                if (lane == 0) wait_min64(grpL1, s);
                pr = h2ring + (size_t)((s - 1) & 3) * BH;
            } else {                     // h1[s] @ Wi1^T (critical)
                if (lane == 0) wait_min64(grpL0, s + 1);
                pr = h1ring + (size_t)(s & 3) * BH;
            }
            #pragma unroll
            for (int c = 0; c < 2; ++c) {
                short8 a0[8], a1[8];
                #pragma unroll
                for (int k = 0; k < 8; ++k) {
                    ld_cc16(a0[k], pr + aoff0 + (c * 8 + k) * 32);
                    ld_cc16(a1[k], pr + aoff1 + (c * 8 + k) * 32);
                }
                vm_wait0();
                #pragma unroll
                for (int k = 0; k < 8; ++k) {
                    MFMA16(wreg[c * 8 + k], a0[k], acc0);
                    MFMA16(wreg[c * 8 + k], a1[k], acc1);
                }
            }
        }

        // ---- partials to LDS: D row = feat 4*(lane>>4)+r, col = batch row ----
        #pragma unroll
        for (int r = 0; r < 4; ++r) {
            red[wv][4 * (lane >> 4) + r][lane & 15]      = acc0[r];
            red[wv][4 * (lane >> 4) + r][16 + (lane & 15)] = acc1[r];
        }
        __syncthreads();

        // ---- reduce + tanh + ring store (tid<128) ----
        float v[4];
        if (tid < 128) {
            #pragma unroll
            for (int j = 0; j < 4; ++j) {
                const int ff = r_fg * 4 + j;
                float sum = red[0][ff][r_row] + red[1][ff][r_row]
                          + red[2][ff][r_row] + red[3][ff][r_row] + bias4[j];
                v[j] = tanhf(sum);
            }
            unsigned short* ring_self =
                (layer ? h2ring : h1ring) + (size_t)(s & 3) * BH;
            __hip_atomic_store((unsigned long long*)(ring_self + (size_t)rg * HID + nb),
                               pack4_bf16(v[0], v[1], v[2], v[3]),
                               __ATOMIC_RELAXED, __HIP_MEMORY_SCOPE_AGENT);
        }

        asm volatile("s_waitcnt vmcnt(0)" ::: "memory");   // ring stores at MALL
        __syncthreads();                                   // all waves acked
        if (tid == 0)
            __hip_atomic_store(ep_self, (unsigned)(s + 1),
                               __ATOMIC_RELAXED, __HIP_MEMORY_SCOPE_AGENT);

        // ---- f32 outputs (off critical path, after signal) ----
        if (tid < 128) {
            if (layer == 1) {
                *(float4*)(out + (size_t)s * BH + (size_t)rg * HID + nb) =
                    make_float4(v[0], v[1], v[2], v[3]);
                if (s == SEQ - 1)
                    *(float4*)(out + (size_t)SEQ * BH + BH + (size_t)rg * HID + nb) =
                        make_float4(v[0], v[1], v[2], v[3]);     // h_final[1]
            } else if (s == SEQ - 1) {
                *(float4*)(out + (size_t)SEQ * BH + (size_t)rg * HID + nb) =
                    make_float4(v[0], v[1], v[2], v[3]);         // h_final[0]
            }
        }
    }
}

extern "C" void kernel_launch(void* const* d_in, const int* in_sizes, int n_in,
                              void* d_out, int out_size, void* d_ws, size_t ws_size,
                              hipStream_t stream) {
    const float* xp   = (const float*)d_in[0];
    const float* Wi0p = (const float*)d_in[1];
    const float* bi0p = (const float*)d_in[2];
    const float* Wh0p = (const float*)d_in[3];
    const float* bh0p = (const float*)d_in[4];
    const float* Wi1p = (const float*)d_in[5];
    const float* bi1p = (const float*)d_in[6];
    const float* Wh1p = (const float*)d_in[7];
    const float* bh1p = (const float*)d_in[8];
    float* outp = (float*)d_out;

    // ws layout: rings 1 MiB | flags 4 KiB | xb 64 MiB
    unsigned short* rings = (unsigned short*)d_ws;
    const size_t ring_bytes = (size_t)8 * BH * sizeof(unsigned short);  // 1 MiB
    unsigned int* flags = (unsigned int*)((char*)d_ws + ring_bytes);
    const size_t flag_pad = 4096;
    unsigned short* xb = (unsigned short*)((char*)d_ws + ring_bytes + flag_pad);
    const size_t xb_bytes = (size_t)SEQ * BH * 2;                        // 64 MiB
    const int use_xb = (ws_size >= ring_bytes + flag_pad + xb_bytes) ? 1 : 0;

    {
        const int n16 = (int)((ring_bytes + flag_pad) / 16);
        init_ws<<<(n16 + 255) / 256, 256, 0, stream>>>((uint4*)d_ws, n16);
    }
    if (use_xb)
        cvt_f32_bf16<<<2048, 256, 0, stream>>>(xp, xb, SEQ * BH / 4);

    rnn_mfma<<<dim3(256), dim3(256), 0, stream>>>(
        xp, xb, use_xb,
        Wi0p, bi0p, Wh0p, bh0p, Wi1p, bi1p, Wh1p, bh1p,
        outp, rings, flags);
}